// Round 1
// baseline (90.164 us; speedup 1.0000x reference)
//
#include <hip/hip_runtime.h>
#include <math.h>

#define DIM 16
#define NQ 4
#define NL 3
#define VQC_BATCH 524288

// ---------------------------------------------------------------------------
// Prep kernel: build the fixed 16x16 complex unitary U for the 3 weight layers
// (CNOT ring + RY + RZ per qubit). One thread per column; double precision
// internally (cost is irrelevant - one tiny block), stored as fp32.
// Layout (row-major, re/im interleaved): U[(j*16 + i)*2 + {0,1}] = U_{j,i}
// ---------------------------------------------------------------------------
__global__ __launch_bounds__(64) void vqc_prep(const float* __restrict__ w,
                                               float* __restrict__ U) {
  const int col = threadIdx.x;
  if (col >= DIM) return;
  double sr[DIM], si[DIM];
#pragma unroll
  for (int k = 0; k < DIM; ++k) { sr[k] = (k == col) ? 1.0 : 0.0; si[k] = 0.0; }

#pragma unroll
  for (int layer = 0; layer < NL; ++layer) {
    // CNOT ring: new[idx] = old[perm[idx]], perm = idx ^ (cbit(c) << (3-t))
#pragma unroll
    for (int c = 0; c < NQ; ++c) {
      const int t = (c + 1) & 3;
      double tr[DIM], ti[DIM];
#pragma unroll
      for (int idx = 0; idx < DIM; ++idx) {
        const int cbit = (idx >> (3 - c)) & 1;
        const int src = idx ^ (cbit << (3 - t));
        tr[idx] = sr[src]; ti[idx] = si[src];
      }
#pragma unroll
      for (int idx = 0; idx < DIM; ++idx) { sr[idx] = tr[idx]; si[idx] = ti[idx]; }
    }
    // per qubit: RY(w[l][q][0]) then RZ(w[l][q][1])
#pragma unroll
    for (int q = 0; q < NQ; ++q) {
      const int m = 8 >> q;
      {
        const double th = 0.5 * (double)w[(layer * NQ + q) * 2 + 0];
        const double c = cos(th), s = sin(th);
#pragma unroll
        for (int idx = 0; idx < DIM; ++idx) {
          if ((idx & m) == 0) {
            const int i1 = idx | m;
            const double a0r = sr[idx], a0i = si[idx];
            const double a1r = sr[i1], a1i = si[i1];
            sr[idx] = c * a0r - s * a1r;  si[idx] = c * a0i - s * a1i;
            sr[i1]  = s * a0r + c * a1r;  si[i1]  = s * a0i + c * a1i;
          }
        }
      }
      {
        const double ph = 0.5 * (double)w[(layer * NQ + q) * 2 + 1];
        const double ch = cos(ph), sh = sin(ph);
#pragma unroll
        for (int idx = 0; idx < DIM; ++idx) {
          const double ar = sr[idx], ai = si[idx];
          if (idx & m) { sr[idx] = ch * ar - sh * ai; si[idx] = ch * ai + sh * ar; }
          else         { sr[idx] = ch * ar + sh * ai; si[idx] = ch * ai - sh * ar; }
        }
      }
    }
  }
  // thread col owns column col: write row-major
#pragma unroll
  for (int j = 0; j < DIM; ++j) {
    U[(j * DIM + col) * 2 + 0] = (float)sr[j];
    U[(j * DIM + col) * 2 + 1] = (float)si[j];
  }
}

// ---------------------------------------------------------------------------
// Main kernel: one thread per batch element.
//   s = product state from RY(x) (real, rank-1)     ~70 VALU
//   v = U s (complex matvec, U via uniform s_loads) 512 FMA
//   p = |v|^2, then sign-butterfly for the 4 Z-expectations
// ---------------------------------------------------------------------------
__global__ __launch_bounds__(256) void vqc_main(const float4* __restrict__ x4,
                                                const float* __restrict__ U,
                                                float4* __restrict__ out4) {
  const int b = blockIdx.x * 256 + threadIdx.x;
  const float4 xv = x4[b];

  float s0, c0, s1, c1, s2, c2, s3, c3;
  __sincosf(0.5f * xv.x, &s0, &c0);
  __sincosf(0.5f * xv.y, &s1, &c1);
  __sincosf(0.5f * xv.z, &s2, &c2);
  __sincosf(0.5f * xv.w, &s3, &c3);

  // product state: idx bit3 = wire0 ... bit0 = wire3; bit=0 -> cos, 1 -> sin
  float ab[4], cd[4];
  ab[0] = c0 * c1; ab[1] = c0 * s1; ab[2] = s0 * c1; ab[3] = s0 * s1;
  cd[0] = c2 * c3; cd[1] = c2 * s3; cd[2] = s2 * c3; cd[3] = s2 * s3;
  float sv[DIM];
#pragma unroll
  for (int hi = 0; hi < 4; ++hi)
#pragma unroll
    for (int lo = 0; lo < 4; ++lo)
      sv[hi * 4 + lo] = ab[hi] * cd[lo];

  // v = U s ; p = |v|^2. U loads are wave-uniform -> SGPRs.
  float p[DIM];
#pragma unroll
  for (int j = 0; j < DIM; ++j) {
    float vr = 0.f, vi = 0.f;
#pragma unroll
    for (int i = 0; i < DIM; ++i) {
      const float ur = U[(j * DIM + i) * 2 + 0];
      const float ui = U[(j * DIM + i) * 2 + 1];
      vr = __builtin_fmaf(ur, sv[i], vr);
      vi = __builtin_fmaf(ui, sv[i], vi);
    }
    p[j] = vr * vr + vi * vi;
  }

  // sign butterfly: z_w = sum_j (1-2*bit_{3-w}(j)) * p_j
  float a[8], z3 = 0.f;
#pragma unroll
  for (int t = 0; t < 8; ++t) { a[t] = p[2 * t] + p[2 * t + 1]; z3 += p[2 * t] - p[2 * t + 1]; }
  float b2[4], z2 = 0.f;
#pragma unroll
  for (int t = 0; t < 4; ++t) { b2[t] = a[2 * t] + a[2 * t + 1]; z2 += a[2 * t] - a[2 * t + 1]; }
  const float e0 = b2[0] + b2[1], e1 = b2[2] + b2[3];
  const float z1 = (b2[0] - b2[1]) + (b2[2] - b2[3]);
  const float z0 = e0 - e1;

  out4[b] = make_float4(z0, z1, z2, z3);
}

extern "C" void kernel_launch(void* const* d_in, const int* in_sizes, int n_in,
                              void* d_out, int out_size, void* d_ws, size_t ws_size,
                              hipStream_t stream) {
  const float* x = (const float*)d_in[0];
  const float* w = (const float*)d_in[1];
  float* U = (float*)d_ws;  // 512 floats = 2 KB scratch

  vqc_prep<<<1, 64, 0, stream>>>(w, U);
  vqc_main<<<VQC_BATCH / 256, 256, 0, stream>>>((const float4*)x, U, (float4*)d_out);
}

// Round 2
// 72.388 us; speedup vs baseline: 1.2456x; 1.2456x over previous
//
#include <hip/hip_runtime.h>
#include <math.h>

#define DIM 16
#define NQ 4
#define NL 3
#define VQC_BATCH 524288

// ---------------------------------------------------------------------------
// Prep kernel: build the fixed 16x16 complex unitary U for the 3 weight layers
// (CNOT ring + RY + RZ per qubit). One thread per column. fp32 + native
// sincos: weights are O(0.1), native trig error ~1e-6 — far below tolerance.
// Layout (row-major, re/im interleaved): U[(j*16 + i)*2 + {0,1}] = U_{j,i}
// ---------------------------------------------------------------------------
__global__ __launch_bounds__(64) void vqc_prep(const float* __restrict__ w,
                                               float* __restrict__ U) {
  const int col = threadIdx.x;
  if (col >= DIM) return;
  float sr[DIM], si[DIM];
#pragma unroll
  for (int k = 0; k < DIM; ++k) { sr[k] = (k == col) ? 1.f : 0.f; si[k] = 0.f; }

#pragma unroll
  for (int layer = 0; layer < NL; ++layer) {
    // CNOT ring: new[idx] = old[perm[idx]], perm = idx ^ (cbit(c) << (3-t))
#pragma unroll
    for (int c = 0; c < NQ; ++c) {
      const int t = (c + 1) & 3;
      float tr[DIM], ti[DIM];
#pragma unroll
      for (int idx = 0; idx < DIM; ++idx) {
        const int cbit = (idx >> (3 - c)) & 1;
        const int src = idx ^ (cbit << (3 - t));
        tr[idx] = sr[src]; ti[idx] = si[src];
      }
#pragma unroll
      for (int idx = 0; idx < DIM; ++idx) { sr[idx] = tr[idx]; si[idx] = ti[idx]; }
    }
    // per qubit: RY(w[l][q][0]) then RZ(w[l][q][1])
#pragma unroll
    for (int q = 0; q < NQ; ++q) {
      const int m = 8 >> q;
      {
        float s, c;
        __sincosf(0.5f * w[(layer * NQ + q) * 2 + 0], &s, &c);
#pragma unroll
        for (int idx = 0; idx < DIM; ++idx) {
          if ((idx & m) == 0) {
            const int i1 = idx | m;
            const float a0r = sr[idx], a0i = si[idx];
            const float a1r = sr[i1], a1i = si[i1];
            sr[idx] = c * a0r - s * a1r;  si[idx] = c * a0i - s * a1i;
            sr[i1]  = s * a0r + c * a1r;  si[i1]  = s * a0i + c * a1i;
          }
        }
      }
      {
        float sh, ch;
        __sincosf(0.5f * w[(layer * NQ + q) * 2 + 1], &sh, &ch);
#pragma unroll
        for (int idx = 0; idx < DIM; ++idx) {
          const float ar = sr[idx], ai = si[idx];
          if (idx & m) { sr[idx] = ch * ar - sh * ai; si[idx] = ch * ai + sh * ar; }
          else         { sr[idx] = ch * ar + sh * ai; si[idx] = ch * ai - sh * ar; }
        }
      }
    }
  }
  // thread col owns column col: write row-major
#pragma unroll
  for (int j = 0; j < DIM; ++j) {
    U[(j * DIM + col) * 2 + 0] = sr[j];
    U[(j * DIM + col) * 2 + 1] = si[j];
  }
}

// ---------------------------------------------------------------------------
// Main kernel: one thread per batch element.
//   s = product state from RY(x) (real, rank-1)     ~70 VALU
//   v = U s (complex matvec; U rows via float4)     512 FMA
//   p = |v|^2, then sign-butterfly for the 4 Z-expectations
// ---------------------------------------------------------------------------
__global__ __launch_bounds__(256) void vqc_main(const float4* __restrict__ x4,
                                                const float4* __restrict__ U4,
                                                float4* __restrict__ out4) {
  const int b = blockIdx.x * 256 + threadIdx.x;
  const float4 xv = x4[b];

  float s0, c0, s1, c1, s2, c2, s3, c3;
  __sincosf(0.5f * xv.x, &s0, &c0);
  __sincosf(0.5f * xv.y, &s1, &c1);
  __sincosf(0.5f * xv.z, &s2, &c2);
  __sincosf(0.5f * xv.w, &s3, &c3);

  // product state: idx bit3 = wire0 ... bit0 = wire3; bit=0 -> cos, 1 -> sin
  float ab[4], cd[4];
  ab[0] = c0 * c1; ab[1] = c0 * s1; ab[2] = s0 * c1; ab[3] = s0 * s1;
  cd[0] = c2 * c3; cd[1] = c2 * s3; cd[2] = s2 * c3; cd[3] = s2 * s3;
  float sv[DIM];
#pragma unroll
  for (int hi = 0; hi < 4; ++hi)
#pragma unroll
    for (int lo = 0; lo < 4; ++lo)
      sv[hi * 4 + lo] = ab[hi] * cd[lo];

  // v = U s ; p = |v|^2. One row = 32 floats = 8 float4 loads (uniform addr).
  float p[DIM];
#pragma unroll
  for (int j = 0; j < DIM; ++j) {
    float vr = 0.f, vi = 0.f;
#pragma unroll
    for (int iv = 0; iv < 8; ++iv) {
      const float4 u = U4[j * 8 + iv];  // (re,im,re,im) for i=2*iv, 2*iv+1
      vr = __builtin_fmaf(u.x, sv[2 * iv], vr);
      vi = __builtin_fmaf(u.y, sv[2 * iv], vi);
      vr = __builtin_fmaf(u.z, sv[2 * iv + 1], vr);
      vi = __builtin_fmaf(u.w, sv[2 * iv + 1], vi);
    }
    p[j] = vr * vr + vi * vi;
  }

  // sign butterfly: z_w = sum_j (1-2*bit_{3-w}(j)) * p_j
  float a[8], z3 = 0.f;
#pragma unroll
  for (int t = 0; t < 8; ++t) { a[t] = p[2 * t] + p[2 * t + 1]; z3 += p[2 * t] - p[2 * t + 1]; }
  float b2[4], z2 = 0.f;
#pragma unroll
  for (int t = 0; t < 4; ++t) { b2[t] = a[2 * t] + a[2 * t + 1]; z2 += a[2 * t] - a[2 * t + 1]; }
  const float e0 = b2[0] + b2[1], e1 = b2[2] + b2[3];
  const float z1 = (b2[0] - b2[1]) + (b2[2] - b2[3]);
  const float z0 = e0 - e1;

  out4[b] = make_float4(z0, z1, z2, z3);
}

extern "C" void kernel_launch(void* const* d_in, const int* in_sizes, int n_in,
                              void* d_out, int out_size, void* d_ws, size_t ws_size,
                              hipStream_t stream) {
  const float* x = (const float*)d_in[0];
  const float* w = (const float*)d_in[1];
  float* U = (float*)d_ws;  // 512 floats = 2 KB scratch

  vqc_prep<<<1, 64, 0, stream>>>(w, U);
  vqc_main<<<VQC_BATCH / 256, 256, 0, stream>>>((const float4*)x, (const float4*)U,
                                                (float4*)d_out);
}